// Round 1
// 330.741 us; speedup vs baseline: 1.0938x; 1.0938x over previous
//
#include <hip/hip_runtime.h>
#include <math.h>

// Problem constants:
//   WH=WW=16, N=256 tokens/window, H=6 heads, DIM=192, hd=32
//   B_=256 windows, nW=64 mask windows, qk_scale = 32^-0.5
#define N_TOK 256
#define NHEADS 6
#define DIM_C 192
#define HD 32
#define B_WIN 256

typedef short bf16x8 __attribute__((ext_vector_type(8)));   // 8 bf16 in 4 VGPRs
typedef float f32x4 __attribute__((ext_vector_type(4)));

__device__ inline short f2bf(float f) {          // RNE
    unsigned u = __float_as_uint(f);
    u = (u + 0x7fffu + ((u >> 16) & 1u)) >> 16;
    return (short)u;
}
__device__ inline short f2bf_fast(float f) {     // round-half-up (0.5 ulp)
    return (short)((__float_as_uint(f) + 0x8000u) >> 16);
}
__device__ inline float bf2f(short s) {
    return __uint_as_float(((unsigned)(unsigned short)s) << 16);
}

// ---------------------------------------------------------------------------
// Kernel 1: CPB MLP -> table (961 x 6) fp32
// ---------------------------------------------------------------------------
__global__ __launch_bounds__(512) void cpb_table_kernel(
    const float* __restrict__ scale, const float* __restrict__ w1,
    const float* __restrict__ b1, const float* __restrict__ w2,
    const float* __restrict__ b2, float* __restrict__ table)
{
    __shared__ float red[512];
    const int e = blockIdx.x;            // 0..960
    const int i = e / 31, j = e % 31;
    const float t0 = ((float)(i - 15)) * (8.0f / 15.0f);
    const float t1 = ((float)(j - 15)) * (8.0f / 15.0f);
    const float s0 = scale[0], s1 = scale[1];
    const int t = threadIdx.x;
    const float* w = w1 + t * 4;
    float h = w[0] * t0 + w[1] * t1 + w[2] * s0 + w[3] * s1 + b1[t];
    h = fmaxf(h, 0.0f);
    for (int head = 0; head < NHEADS; ++head) {
        red[t] = h * w2[head * 512 + t];
        __syncthreads();
        for (int s = 256; s > 0; s >>= 1) {
            if (t < s) red[t] += red[t + s];
            __syncthreads();
        }
        if (t == 0) table[e * NHEADS + head] = red[0] + b2[head];
        __syncthreads();
    }
}

// ---------------------------------------------------------------------------
// MFMA-C-layout permuted index helper. Slab layout (65536 bf16):
//   offset = ((rb*8 + g)*64 + lane)*8 + (nt&1)*4 + r
//   where row = rb*16 + (lane>>4)*4 + r,  col = nt*16 + (lane&15),  nt = 2g+(j>>2)
// Thread j in [0,8): nt = 2g + (j>>2), r = j&3.
// ---------------------------------------------------------------------------

// Kernel 2a: bias -> permuted bf16 (6 slabs). One thread per 8 outputs.
__global__ __launch_bounds__(256) void bias_perm_kernel(
    const float* __restrict__ table, short* __restrict__ bias_p)
{
    const int idx8 = blockIdx.x * 256 + threadIdx.x;   // < 6*8192
    const int h = idx8 >> 13;
    const int rem = idx8 & 8191;
    const int rb = rem >> 9;
    const int g = (rem >> 6) & 7;
    const int lane = rem & 63;
    const int quad = lane >> 4, l15 = lane & 15;
    bf16x8 o;
#pragma unroll
    for (int j = 0; j < 8; ++j) {
        const int nt = g * 2 + (j >> 2), r = j & 3;
        const int row = rb * 16 + quad * 4 + r;
        const int col = nt * 16 + l15;
        const int rel0 = (row >> 4) - (col >> 4) + 15;
        const int rel1 = (row & 15) - (col & 15) + 15;
        o[j] = f2bf(table[(rel0 * 31 + rel1) * NHEADS + h]);
    }
    ((bf16x8*)bias_p)[idx8] = o;
}

// Kernel 2b: mask -> permuted bf16 (64 slabs).
__global__ __launch_bounds__(256) void mask_perm_kernel(
    const float* __restrict__ mask, short* __restrict__ mask_p)
{
    const int idx8 = blockIdx.x * 256 + threadIdx.x;   // < 64*8192
    const int bw = idx8 >> 13;
    const int rem = idx8 & 8191;
    const int rb = rem >> 9;
    const int g = (rem >> 6) & 7;
    const int lane = rem & 63;
    const int quad = lane >> 4, l15 = lane & 15;
    const float* ms = mask + ((size_t)bw << 16);
    bf16x8 o;
#pragma unroll
    for (int j = 0; j < 8; ++j) {
        const int nt = g * 2 + (j >> 2), r = j & 3;
        const int row = rb * 16 + quad * 4 + r;
        const int col = nt * 16 + l15;
        o[j] = f2bf(ms[row * 256 + col]);
    }
    ((bf16x8*)mask_p)[idx8] = o;
}

// ---------------------------------------------------------------------------
// Kernel 2c: generic fp32 -> bf16 (n4 = count/4)
// ---------------------------------------------------------------------------
__global__ __launch_bounds__(256) void f32_to_bf16_kernel(
    const float* __restrict__ in, short* __restrict__ out, int n4)
{
    const int i = blockIdx.x * 256 + threadIdx.x;
    if (i < n4) {
        float4 v = ((const float4*)in)[i];
        short4 s;
        s.x = f2bf(v.x); s.y = f2bf(v.y); s.z = f2bf(v.z); s.w = f2bf(v.w);
        ((short4*)out)[i] = s;
    }
}

// ---------------------------------------------------------------------------
// Kernel 3: QKV GEMM via MFMA, no LDS. C(65536,576) = x16(65536,192)*W^T + b.
// ---------------------------------------------------------------------------
__global__ __launch_bounds__(256) void qkv_gemm_kernel(
    const short* __restrict__ x16, const short* __restrict__ w16,
    const float* __restrict__ qkv_b,
    short* __restrict__ qb, short* __restrict__ kb, short* __restrict__ vb)
{
    const int t = threadIdx.x;
    const int lane = t & 63;
    const int w = t >> 6;
    const int l15 = lane & 15, quad = lane >> 4;
    const int n0 = blockIdx.x * 64;
    const int m0 = blockIdx.y * 128 + w * 32;

    f32x4 acc[2][4] = {};
#pragma unroll
    for (int ks = 0; ks < 6; ++ks) {
        bf16x8 af[2];
#pragma unroll
        for (int mt = 0; mt < 2; ++mt)
            af[mt] = *(const bf16x8*)(x16 + (size_t)(m0 + mt * 16 + l15) * DIM_C + ks * 32 + quad * 8);
        bf16x8 bfr[4];
#pragma unroll
        for (int nt = 0; nt < 4; ++nt)
            bfr[nt] = *(const bf16x8*)(w16 + (size_t)(n0 + nt * 16 + l15) * DIM_C + ks * 32 + quad * 8);
#pragma unroll
        for (int mt = 0; mt < 2; ++mt)
#pragma unroll
            for (int nt = 0; nt < 4; ++nt)
                acc[mt][nt] = __builtin_amdgcn_mfma_f32_16x16x32_bf16(af[mt], bfr[nt], acc[mt][nt], 0, 0, 0);
    }

    const int which = n0 / DIM_C;                   // constant per block
    short* outp = (which == 0) ? qb : (which == 1) ? kb : vb;
    const float qscale = (which == 0) ? 0.17677669529663689f : 1.0f;
#pragma unroll
    for (int mt = 0; mt < 2; ++mt) {
#pragma unroll
        for (int r = 0; r < 4; ++r) {
            const int m = m0 + mt * 16 + quad * 4 + r;
            const int b = m >> 8, tok = m & 255;
#pragma unroll
            for (int nt = 0; nt < 4; ++nt) {
                const int c = n0 + nt * 16 + l15;
                const int rem = c - which * DIM_C;
                const int h = rem >> 5, d = rem & 31;
                const float val = (acc[mt][nt][r] + qkv_b[c]) * qscale;
                outp[((size_t)((b * NHEADS + h) * N_TOK + tok)) * HD + d] = f2bf(val);
            }
        }
    }
}

// ---------------------------------------------------------------------------
// Kernel 5: proj GEMM via MFMA, no LDS. out(65536,192) = ao*W^T + b, fp32 out.
// ---------------------------------------------------------------------------
__global__ __launch_bounds__(256) void proj_gemm_kernel(
    const short* __restrict__ A16, const short* __restrict__ w16,
    const float* __restrict__ proj_b, float* __restrict__ out)
{
    const int t = threadIdx.x;
    const int lane = t & 63;
    const int w = t >> 6;
    const int l15 = lane & 15, quad = lane >> 4;
    const int n0 = blockIdx.x * 64;
    const int m0 = blockIdx.y * 128 + w * 32;

    f32x4 acc[2][4] = {};
#pragma unroll
    for (int ks = 0; ks < 6; ++ks) {
        bf16x8 af[2];
#pragma unroll
        for (int mt = 0; mt < 2; ++mt)
            af[mt] = *(const bf16x8*)(A16 + (size_t)(m0 + mt * 16 + l15) * DIM_C + ks * 32 + quad * 8);
        bf16x8 bfr[4];
#pragma unroll
        for (int nt = 0; nt < 4; ++nt)
            bfr[nt] = *(const bf16x8*)(w16 + (size_t)(n0 + nt * 16 + l15) * DIM_C + ks * 32 + quad * 8);
#pragma unroll
        for (int mt = 0; mt < 2; ++mt)
#pragma unroll
            for (int nt = 0; nt < 4; ++nt)
                acc[mt][nt] = __builtin_amdgcn_mfma_f32_16x16x32_bf16(af[mt], bfr[nt], acc[mt][nt], 0, 0, 0);
    }

#pragma unroll
    for (int mt = 0; mt < 2; ++mt) {
#pragma unroll
        for (int r = 0; r < 4; ++r) {
            const int m = m0 + mt * 16 + quad * 4 + r;
#pragma unroll
            for (int nt = 0; nt < 4; ++nt) {
                const int c = n0 + nt * 16 + l15;
                out[(size_t)m * DIM_C + c] = acc[mt][nt][r] + proj_b[c];
            }
        }
    }
}

// ---------------------------------------------------------------------------
// Kernel 4: MFMA attention per (b,h), wave-owns-rows structure.
// Changes this round:
//  - 1D grid + XCD-aware swizzle: all 24 blocks sharing a mask slab (bw)
//    run consecutively on one XCD (dispatch round-robins linear%8), so the
//    128 KB mask slab is fetched into that XCD's L2 once instead of 24x.
//  - K fragments hoisted into registers once per block (chunk-invariant);
//    removes 48 of 64 global K loads per lane and shortens the per-chunk
//    dependency chain.
//  - bias+mask fed as the MFMA C operand (tables are pre-permuted to the
//    exact C layout): removes the separate S+=bias+mask pass and the
//    accumulator zero-init; table loads issue before each half's MFMAs.
// ---------------------------------------------------------------------------
#define PS_LD 264   // shorts; 528 B/row (16B aligned)

__global__ __launch_bounds__(256, 3) void attn_mfma_kernel(
    const short* __restrict__ q, const short* __restrict__ k,
    const short* __restrict__ v, const short* __restrict__ bias_p,
    const short* __restrict__ mask_p, short* __restrict__ out16)
{
    __shared__ __align__(16) short Vt[32][PS_LD];      // V^T, 16.9 KB
    __shared__ __align__(16) short Pw[4][16][PS_LD];   // per-wave P, 33.8 KB

    // XCD-aware swizzle (bijective on 1536 = 8 xcd * 8 bw-groups * 24 jobs):
    //   xcd  = l & 7      -> owns bw with bw%8 == xcd
    //   bw   = xcd + 8*(s/24), s = l>>3
    //   j    = s % 24     -> (h, b>>6)
    const int l = blockIdx.x;            // 0..1535
    const int s = l >> 3;                // 0..191
    const int bw = (l & 7) + 8 * (s / 24);
    const int j = s % 24;
    const int h = j % 6;                 // 0..5
    const int b = (j / 6) * 64 + bw;     // 0..255

    const int t = threadIdx.x;
    const int lane = t & 63;
    const int w = t >> 6;
    const int l15 = lane & 15;
    const int quad = lane >> 4;
    const size_t slab = ((size_t)(b * NHEADS + h)) * (N_TOK * HD);

    // stage V^T (thread t -> token t), swizzled columns
    {
        const bf16x8* vrow = (const bf16x8*)(v + slab + (size_t)t * HD);
#pragma unroll
        for (int u = 0; u < 4; ++u) {
            bf16x8 vv = vrow[u];
#pragma unroll
            for (int jj = 0; jj < 8; ++jj) {
                const int d = u * 8 + jj;
                Vt[d][t ^ (((d >> 3) & 1) * 16)] = vv[jj];
            }
        }
    }

    // K fragments: chunk-invariant, load once (16 x bf16x8 = 64 VGPRs)
    bf16x8 kfr[16];
#pragma unroll
    for (int nt = 0; nt < 16; ++nt)
        kfr[nt] = *(const bf16x8*)(k + slab + (size_t)(nt * 16 + l15) * HD + quad * 8);

    __syncthreads();   // Vt ready (only barrier in the kernel body)

    const short* bslab = bias_p + h * 65536;
    const short* mslab = mask_p + bw * 65536;

    for (int chunk = 0; chunk < 4; ++chunk) {
        const int rb = chunk * 4 + w;    // row block 0..15

        // Q fragment: rows rb*16 + l15, k = quad*8..+7
        const bf16x8 qf = *(const bf16x8*)(q + slab + (size_t)(rb * 16 + l15) * HD + quad * 8);

        // QK^T with bias+mask injected as C:
        // C-layout: row = rb*16+quad*4+r, col = nt*16+l15
        f32x4 S[16];
#pragma unroll
        for (int half = 0; half < 2; ++half) {
            bf16x8 bb[4], mm[4];
#pragma unroll
            for (int gg = 0; gg < 4; ++gg) {
                const int g = half * 4 + gg;
                const int off = ((rb * 8 + g) * 64 + lane) * 8;
                bb[gg] = *(const bf16x8*)(bslab + off);
                mm[gg] = *(const bf16x8*)(mslab + off);
            }
#pragma unroll
            for (int gg = 0; gg < 4; ++gg) {
                const int g = half * 4 + gg;
                f32x4 c0, c1;
#pragma unroll
                for (int r = 0; r < 4; ++r) {
                    c0[r] = bf2f(bb[gg][r])     + bf2f(mm[gg][r]);
                    c1[r] = bf2f(bb[gg][4 + r]) + bf2f(mm[gg][4 + r]);
                }
                S[g * 2]     = __builtin_amdgcn_mfma_f32_16x16x32_bf16(qf, kfr[g * 2],     c0, 0, 0, 0);
                S[g * 2 + 1] = __builtin_amdgcn_mfma_f32_16x16x32_bf16(qf, kfr[g * 2 + 1], c1, 0, 0, 0);
            }
        }

        // row max over register tiles, then across l15 lanes
        float mx[4] = {-1e30f, -1e30f, -1e30f, -1e30f};
#pragma unroll
        for (int nt = 0; nt < 16; ++nt)
#pragma unroll
            for (int r = 0; r < 4; ++r)
                mx[r] = fmaxf(mx[r], S[nt][r]);
#pragma unroll
        for (int r = 0; r < 4; ++r) {
            mx[r] = fmaxf(mx[r], __shfl_xor(mx[r], 1));
            mx[r] = fmaxf(mx[r], __shfl_xor(mx[r], 2));
            mx[r] = fmaxf(mx[r], __shfl_xor(mx[r], 4));
            mx[r] = fmaxf(mx[r], __shfl_xor(mx[r], 8));
        }

        // exp + row sum + P -> per-wave LDS (swizzled)
        float sm[4] = {0.f, 0.f, 0.f, 0.f};
#pragma unroll
        for (int nt = 0; nt < 16; ++nt) {
#pragma unroll
            for (int r = 0; r < 4; ++r) {
                const float p = __expf(S[nt][r] - mx[r]);
                sm[r] += p;
                const int lr = quad * 4 + r;
                Pw[w][lr][(nt * 16 + l15) ^ (((lr >> 3) & 1) * 16)] = f2bf_fast(p);
            }
        }
        float inv[4];
#pragma unroll
        for (int r = 0; r < 4; ++r) {
            sm[r] += __shfl_xor(sm[r], 1);
            sm[r] += __shfl_xor(sm[r], 2);
            sm[r] += __shfl_xor(sm[r], 4);
            sm[r] += __shfl_xor(sm[r], 8);
            inv[r] = __builtin_amdgcn_rcpf(sm[r]);
        }

        // wave-local LDS: drain writes before fragment reads
        __asm__ volatile("s_waitcnt lgkmcnt(0)" ::: "memory");

        // PV: O (16 rows x 32 d), A-frags from own Pw, B-frags from Vt
        f32x4 O0 = {0.f, 0.f, 0.f, 0.f};
        f32x4 O1 = {0.f, 0.f, 0.f, 0.f};
        const int sw = ((l15 >> 3) & 1) * 16;
#pragma unroll
        for (int ks = 0; ks < 8; ++ks) {
            const int cb = ks * 32 + quad * 8;
            bf16x8 af  = *(const bf16x8*)&Pw[w][l15][cb ^ sw];
            bf16x8 bf0 = *(const bf16x8*)&Vt[l15][cb ^ sw];
            bf16x8 bf1 = *(const bf16x8*)&Vt[16 + l15][cb ^ sw];
            O0 = __builtin_amdgcn_mfma_f32_16x16x32_bf16(af, bf0, O0, 0, 0, 0);
            O1 = __builtin_amdgcn_mfma_f32_16x16x32_bf16(af, bf1, O1, 0, 0, 0);
        }

        // epilogue: rows quad*4+r match this thread's inv[r]
#pragma unroll
        for (int r = 0; r < 4; ++r) {
            const int token = rb * 16 + quad * 4 + r;
            short* dst = out16 + ((size_t)(b * N_TOK + token)) * DIM_C + h * HD;
            dst[l15]      = f2bf_fast(O0[r] * inv[r]);
            dst[16 + l15] = f2bf_fast(O1[r] * inv[r]);
        }
    }
}

// ---------------------------------------------------------------------------
// Launch
// ---------------------------------------------------------------------------
extern "C" void kernel_launch(void* const* d_in, const int* in_sizes, int n_in,
                              void* d_out, int out_size, void* d_ws, size_t ws_size,
                              hipStream_t stream)
{
    const float* x      = (const float*)d_in[0];   // (256,256,192)
    const float* scale  = (const float*)d_in[1];   // (1,2)
    const float* mask   = (const float*)d_in[2];   // (64,256,256)
    const float* qkv_w  = (const float*)d_in[3];   // (576,192)
    const float* qkv_b  = (const float*)d_in[4];   // (576,)
    const float* cpb_w1 = (const float*)d_in[5];   // (512,4)
    const float* cpb_b1 = (const float*)d_in[6];   // (512,)
    const float* cpb_w2 = (const float*)d_in[7];   // (6,512)
    const float* cpb_b2 = (const float*)d_in[8];   // (6,)
    const float* proj_w = (const float*)d_in[9];   // (192,192)
    const float* proj_b = (const float*)d_in[10];  // (192,)
    float* out = (float*)d_out;                    // (256,256,192) fp32

    const size_t per = (size_t)B_WIN * NHEADS * N_TOK * HD;  // 12,582,912
    short* wss     = (short*)d_ws;
    short* qb      = wss;
    short* kb      = qb + per;
    short* vb      = kb + per;
    short* ao      = vb + per;
    short* x16     = ao + per;                    // 12,582,912
    short* bias_p  = x16 + per;                   // 6*65536  =   393,216
    short* mask_p  = bias_p + 393216;             // 64*65536 = 4,194,304
    short* qkvw16  = mask_p + 4194304;            // 110,592
    short* projw16 = qkvw16 + 110592;             // 36,864
    float* table   = (float*)(projw16 + 36864);   // 961*6 fp32

    cpb_table_kernel<<<961, 512, 0, stream>>>(scale, cpb_w1, cpb_b1, cpb_w2, cpb_b2, table);

    bias_perm_kernel<<<(NHEADS * 8192) / 256, 256, 0, stream>>>(table, bias_p);
    mask_perm_kernel<<<(64 * 8192) / 256, 256, 0, stream>>>(mask, mask_p);

    f32_to_bf16_kernel<<<(int)((per / 4 + 255) / 256), 256, 0, stream>>>(x, x16, (int)(per / 4));
    f32_to_bf16_kernel<<<(110592 / 4 + 255) / 256, 256, 0, stream>>>(qkv_w, qkvw16, 110592 / 4);
    f32_to_bf16_kernel<<<(36864 / 4 + 255) / 256, 256, 0, stream>>>(proj_w, projw16, 36864 / 4);

    qkv_gemm_kernel<<<dim3(9, 512), 256, 0, stream>>>(x16, qkvw16, qkv_b, qb, kb, vb);

    attn_mfma_kernel<<<NHEADS * B_WIN, 256, 0, stream>>>(qb, kb, vb, bias_p, mask_p, ao);

    proj_gemm_kernel<<<dim3(3, 512), 256, 0, stream>>>(ao, projw16, proj_b, out);
}